// Round 4
// 825.470 us; speedup vs baseline: 1.1826x; 1.1826x over previous
//
#include <hip/hip_runtime.h>

#define N_NODES 4096
#define HID 64
#define NH (N_NODES * HID)

typedef float f32x4 __attribute__((ext_vector_type(4)));
typedef short s16x8 __attribute__((ext_vector_type(8)));

__device__ __forceinline__ short f2bf(float f) {
    union { float f; unsigned u; } v; v.f = f;
    unsigned r = v.u + 0x7fffu + ((v.u >> 16) & 1u);  // RTNE
    return (short)(r >> 16);
}

// K1: S = h @ w_self (p==8), BT[r][e][m] = (h @ w_rel[r])[m][e] as bf16 (p<8)
__global__ __launch_bounds__(256) void proj_kernel(
    const float* __restrict__ h, const float* __restrict__ w_self_l,
    const float* __restrict__ w_rel_l, float* __restrict__ S,
    short* __restrict__ BT)
{
    __shared__ float hs[64][65];
    __shared__ float wt[64][64];
    const int tid = threadIdx.x;
    const int mb = blockIdx.x;
    const int p = blockIdx.y;
    const float* w = (p < 8) ? (w_rel_l + p * 64 * 64) : w_self_l;

    #pragma unroll
    for (int i = 0; i < 4; ++i) {
        int idx4 = tid + 256 * i;
        int row = idx4 >> 4, c = idx4 & 15;
        float4 v = *((const float4*)(h + (size_t)(mb * 64 + row) * HID) + c);
        hs[row][c * 4 + 0] = v.x; hs[row][c * 4 + 1] = v.y;
        hs[row][c * 4 + 2] = v.z; hs[row][c * 4 + 3] = v.w;
    }
    #pragma unroll
    for (int i = 0; i < 4; ++i) {
        int idx4 = tid + 256 * i;
        ((float4*)wt)[idx4] = ((const float4*)w)[idx4];
    }
    __syncthreads();

    const int m = tid & 63;
    const int eb = (tid >> 6) * 16;   // wave-uniform
    float acc[16];
    #pragma unroll
    for (int j = 0; j < 16; ++j) acc[j] = 0.f;

    #pragma unroll 4
    for (int d = 0; d < 64; ++d) {
        float hv = hs[m][d];
        const float4* wr = (const float4*)&wt[d][eb];
        float4 w0 = wr[0], w1 = wr[1], w2 = wr[2], w3 = wr[3];
        acc[0]  += hv * w0.x; acc[1]  += hv * w0.y; acc[2]  += hv * w0.z; acc[3]  += hv * w0.w;
        acc[4]  += hv * w1.x; acc[5]  += hv * w1.y; acc[6]  += hv * w1.z; acc[7]  += hv * w1.w;
        acc[8]  += hv * w2.x; acc[9]  += hv * w2.y; acc[10] += hv * w2.z; acc[11] += hv * w2.w;
        acc[12] += hv * w3.x; acc[13] += hv * w3.y; acc[14] += hv * w3.z; acc[15] += hv * w3.w;
    }

    if (p < 8) {
        #pragma unroll
        for (int j = 0; j < 16; ++j)
            BT[(size_t)(p * 64 + eb + j) * N_NODES + mb * 64 + m] = f2bf(acc[j]);
    } else {
        #pragma unroll
        for (int j = 0; j < 16; ++j)
            S[(size_t)(mb * 64 + m) * HID + eb + j] = acc[j];
    }
}

// K2: LDS-staged MFMA GEMM. 16 disjoint partial outputs (r x ks); every output
// word written by exactly ONE block (no cross-r race).
// Round-N change: global loads are now fully COALESCED (adjacent lanes
// contiguous) into a staged LDS tile; MFMA fragments are read from LDS.
// Old version issued loads directly in fragment layout (adjacent lanes 16 KB
// apart -> ~64 line-requests per VMEM instr -> TA/L1-request-bound at
// ~1.7 TB/s). Per-lane K coverage & accumulation order identical to before.
__global__ __launch_bounds__(256, 4) void gemm_kernel(
    const float* __restrict__ A, const short* __restrict__ BT,
    float* __restrict__ msg)
{
    // pad strides chosen so slot index (byte/16) has odd row-stride:
    // As: 68 f32 = 272 B = 17 slots/row; Bs: 72 bf16 = 144 B = 9 slots/row.
    // All frag reads / staging writes are bank-balanced (8-way b128 floor).
    __shared__ float As[64][68];   // 64 x 64 fp32 tile   (17408 B)
    __shared__ short Bs[64][72];   // 64 x 64 bf16 tile   ( 9216 B)

    const int tid = threadIdx.x;
    const int gid = blockIdx.x;
    const int r  = gid & 7;          // relation -> XCD (L2 locality for BT)
    const int rb = (gid >> 3) & 63;  // 64-row tile
    const int ks = gid >> 9;         // K-split half (0/1)
    const int wave = tid >> 6, lane = tid & 63;
    const int quad = lane >> 4, l16 = lane & 15;

    // coalesced staging maps: 16 B per lane, adjacent lanes contiguous
    const int rA = tid >> 4, cA = tid & 15;  // A: 16 chunks/row, rows rA+16j
    const int rB = tid >> 3, cB = tid & 7;   // B:  8 chunks/row, rows rB+32j
    const float* Ag = A  + ((size_t)r * N_NODES + rb * 64) * N_NODES + ks * 2048;
    const short* Bg = BT + ((size_t)r * 64) * N_NODES + ks * 2048;

    f32x4 acc[4];
    #pragma unroll
    for (int nb = 0; nb < 4; ++nb) acc[nb] = (f32x4){0.f, 0.f, 0.f, 0.f};

    // prologue: load tile 0 into regs
    f32x4 a_reg[4];
    s16x8 b_reg[2];
    #pragma unroll
    for (int j = 0; j < 4; ++j)
        a_reg[j] = __builtin_nontemporal_load(
            (const f32x4*)(Ag + (size_t)(rA + 16 * j) * N_NODES + cA * 4));
    #pragma unroll
    for (int j = 0; j < 2; ++j)
        b_reg[j] = *(const s16x8*)(Bg + (size_t)(rB + 32 * j) * N_NODES + cB * 8);

    for (int kk = 0; kk < 32; ++kk) {
        __syncthreads();            // previous tile's frag reads done
        #pragma unroll
        for (int j = 0; j < 4; ++j)
            *(f32x4*)&As[rA + 16 * j][cA * 4] = a_reg[j];
        #pragma unroll
        for (int j = 0; j < 2; ++j)
            *(s16x8*)&Bs[rB + 32 * j][cB * 8] = b_reg[j];

        if (kk < 31) {              // prefetch tile kk+1 (hides HBM latency)
            const int k0 = (kk + 1) * 64;
            #pragma unroll
            for (int j = 0; j < 4; ++j)
                a_reg[j] = __builtin_nontemporal_load(
                    (const f32x4*)(Ag + (size_t)(rA + 16 * j) * N_NODES + k0 + cA * 4));
            #pragma unroll
            for (int j = 0; j < 2; ++j)
                b_reg[j] = *(const s16x8*)(Bg + (size_t)(rB + 32 * j) * N_NODES + k0 + cB * 8);
        }
        __syncthreads();            // tile visible

        #pragma unroll
        for (int s = 0; s < 2; ++s) {
            f32x4 af0 = *(const f32x4*)&As[wave * 16 + l16][s * 32 + quad * 8];
            f32x4 af1 = *(const f32x4*)&As[wave * 16 + l16][s * 32 + quad * 8 + 4];
            s16x8 af;
            af[0] = f2bf(af0[0]); af[1] = f2bf(af0[1]); af[2] = f2bf(af0[2]); af[3] = f2bf(af0[3]);
            af[4] = f2bf(af1[0]); af[5] = f2bf(af1[1]); af[6] = f2bf(af1[2]); af[7] = f2bf(af1[3]);
            #pragma unroll
            for (int nb = 0; nb < 4; ++nb) {
                s16x8 bfr = *(const s16x8*)&Bs[l16 + nb * 16][s * 32 + quad * 8];
                acc[nb] = __builtin_amdgcn_mfma_f32_16x16x32_bf16(af, bfr, acc[nb], 0, 0, 0);
            }
        }
    }

    // partial buffer p = r*2 + ks  (disjoint per block together with rb)
    float* mo = msg + ((size_t)(r * 2 + ks)) * NH;
    // C/D layout: col = l16 (+nb*16), row = quad*4 + i (+wave*16 + rb*64)
    #pragma unroll
    for (int nb = 0; nb < 4; ++nb) {
        #pragma unroll
        for (int i = 0; i < 4; ++i) {
            int orow = rb * 64 + wave * 16 + quad * 4 + i;
            mo[(size_t)orow * HID + nb * 16 + l16] = acc[nb][i];
        }
    }
}

// K3: h_out = relu(S + sum of 16 msg partials)   (float4, 256 blocks x 256 thr)
__global__ __launch_bounds__(256) void relu_kernel(
    const float* __restrict__ S, const float* __restrict__ msg, float* __restrict__ hout)
{
    int i = blockIdx.x * 256 + threadIdx.x;   // float4 index, NH/4 total
    float4 s = ((const float4*)S)[i];
    #pragma unroll
    for (int p = 0; p < 16; ++p) {
        float4 m = ((const float4*)(msg + (size_t)p * NH))[i];
        s.x += m.x; s.y += m.y; s.z += m.z; s.w += m.w;
    }
    float4 o;
    o.x = fmaxf(s.x, 0.f); o.y = fmaxf(s.y, 0.f);
    o.z = fmaxf(s.z, 0.f); o.w = fmaxf(s.w, 0.f);
    ((float4*)hout)[i] = o;
}

// K4: gather with pad-row -> 0
__global__ __launch_bounds__(256) void gather_kernel(
    const float* __restrict__ h2, const int* __restrict__ kw, float* __restrict__ out)
{
    int e = blockIdx.x * 256 + threadIdx.x;   // 131072 total
    int ki = e >> 6, d = e & 63;
    int id = kw[ki];
    out[e] = ((unsigned)id < (unsigned)N_NODES) ? h2[(size_t)id * HID + d] : 0.f;
}

extern "C" void kernel_launch(void* const* d_in, const int* in_sizes, int n_in,
                              void* d_out, int out_size, void* d_ws, size_t ws_size,
                              hipStream_t stream) {
    const float* node_embed = (const float*)d_in[0];   // (4097, 64)
    const float* w_self     = (const float*)d_in[1];   // (2, 64, 64)
    const float* w_rel      = (const float*)d_in[2];   // (2, 8, 64, 64)
    const float* rel_adj    = (const float*)d_in[3];   // (8, 4096, 4096)
    const int*   kw         = (const int*)d_in[4];     // (64, 32)
    float* out = (float*)d_out;                        // (64, 32, 64) fp32

    // workspace carve (23 MB)
    float* msg = (float*)d_ws;                       // 16 * NH f32 partials (r x ks)
    float* S   = msg + 16 * NH;                      // NH f32
    float* h1  = S + NH;                             // NH f32
    float* h2  = h1 + NH;                            // NH f32
    short* BT  = (short*)(h2 + NH);                  // 8*64*4096 bf16

    const float* hin = node_embed;   // layer 0 reads rows 0..4095 only
    float* houts[2] = {h1, h2};
    for (int l = 0; l < 2; ++l) {
        proj_kernel<<<dim3(64, 9), 256, 0, stream>>>(
            hin, w_self + (size_t)l * 64 * 64, w_rel + (size_t)l * 8 * 64 * 64, S, BT);
        gemm_kernel<<<1024, 256, 0, stream>>>(rel_adj, BT, msg);
        relu_kernel<<<256, 256, 0, stream>>>(S, msg, houts[l]);
        hin = houts[l];
    }
    gather_kernel<<<512, 256, 0, stream>>>(h2, kw, out);
}